// Round 9
// baseline (2158.591 us; speedup 1.0000x reference)
//
#include <hip/hip_runtime.h>

#define S_LEN 256
#define BATCH 256

typedef _Float16 f16;
typedef _Float16 f16x8 __attribute__((ext_vector_type(8)));
typedef _Float16 f16x4 __attribute__((ext_vector_type(4)));
typedef float f32x4 __attribute__((ext_vector_type(4)));

__device__ inline float sigf(float x) { return 1.f / (1.f + __expf(-x)); }
__device__ inline float tanhf2(float x) { return 2.f * sigf(2.f * x) - 1.f; }

// ---------------- weight f32 -> f16 conversion ----------------
// dst layout (f16 elems): wihf@0, whhf@65536, wihb@131072, whhb@196608,
// swih@262144, swhh@524288, wwih@786432, wwhh@1048576  (total 1310720)
__global__ void k_convert(const float* __restrict__ w3, const float* __restrict__ w4,
                          const float* __restrict__ w6, const float* __restrict__ w7,
                          const float* __restrict__ w9, const float* __restrict__ w10,
                          const float* __restrict__ w12, const float* __restrict__ w13,
                          f16* __restrict__ dst) {
  int i = blockIdx.x * blockDim.x + threadIdx.x;
  const int n = 1310720;
  for (; i < n; i += gridDim.x * blockDim.x) {
    float v;
    if (i < 262144) {
      int m = i >> 16, j = i & 65535;
      v = (m == 0 ? w3 : m == 1 ? w4 : m == 2 ? w6 : w7)[j];
    } else {
      int k = i - 262144;
      int m = k >> 18, j = k & 262143;
      v = (m == 0 ? w9 : m == 1 ? w10 : m == 2 ? w12 : w13)[j];
    }
    dst[i] = (f16)v;
  }
}

__global__ void k_zero(unsigned* __restrict__ p, int n) {
  int i = blockIdx.x * blockDim.x + threadIdx.x;
  for (; i < n; i += gridDim.x * blockDim.x) p[i] = 0u;
}

// ---------------- embedding gather -> Xf [t][b][128] f16 ----------------
__global__ void k_gather(const int* __restrict__ insts, const float* __restrict__ emb,
                         f16* __restrict__ Xf) {
  int gid = blockIdx.x * blockDim.x + threadIdx.x;  // 0..2097151
  int row = gid >> 5;                               // t*B + b
  int ch = gid & 31;
  int t = row >> 8, b = row & 255;
  int v = insts[b * S_LEN + t];
  const float* src = emb + (size_t)v * 128 + ch * 4;
  f16x4 d;
  d[0] = (f16)src[0]; d[1] = (f16)src[1]; d[2] = (f16)src[2]; d[3] = (f16)src[3];
  *(f16x4*)&Xf[(size_t)row * 128 + ch * 4] = d;
}

// ---------------- char ih precompute: Gih[team][srel][512][16] f16 ----------------
// Gih = x_{t(s)} @ Wih.T + bias  for chain steps s in [sbase, sbase+128).
// Fully parallel over (team, s, gate-rows) -> uses all CUs.
__global__ __launch_bounds__(256)
void k_gih_char(const f16* __restrict__ Wih, const float* __restrict__ bias,
                const f16* __restrict__ Xf, f16* __restrict__ gih,
                int dir, int sbase) {
  const int team = blockIdx.x & 15;
  const int tc = (blockIdx.x >> 4) & 7;
  const int gc = blockIdx.x >> 7;  // 0..1
  const int m0 = team * 16;
  const int lane = threadIdx.x & 63, wave = threadIdx.x >> 6;
  const int l15 = lane & 15, kb = (lane >> 4) * 8;
  const int rbase = gc * 256 + wave * 64;

  f16x8 fw[4][4];
  float bv[4];
#pragma unroll
  for (int tt = 0; tt < 4; ++tt) {
    int col = rbase + tt * 16 + l15;
    bv[tt] = bias[col];
#pragma unroll
    for (int ks = 0; ks < 4; ++ks)
      fw[tt][ks] = *(const f16x8*)&Wih[col * 128 + ks * 32 + kb];
  }

  for (int st = 0; st < 16; ++st) {
    const int s = sbase + tc * 16 + st;
    const int t_in = dir ? (255 - s) : s;
    f32x4 acc[4];
#pragma unroll
    for (int tt = 0; tt < 4; ++tt) { f32x4 a = {bv[tt], bv[tt], bv[tt], bv[tt]}; acc[tt] = a; }
    f16x8 ax[4];
#pragma unroll
    for (int ks = 0; ks < 4; ++ks)
      ax[ks] = *(const f16x8*)&Xf[(size_t)t_in * BATCH * 128 + (m0 + l15) * 128 + ks * 32 + kb];
#pragma unroll
    for (int ks = 0; ks < 4; ++ks)
#pragma unroll
      for (int tt = 0; tt < 4; ++tt)
        acc[tt] = __builtin_amdgcn_mfma_f32_16x16x32_f16(ax[ks], fw[tt][ks], acc[tt], 0, 0, 0);
#pragma unroll
    for (int tt = 0; tt < 4; ++tt) {
      f16x4 o;
#pragma unroll
      for (int r = 0; r < 4; ++r) o[r] = (f16)acc[tt][r];
      size_t off = ((size_t)(team * 128 + (s - sbase)) * 512 + rbase + tt * 16 + l15) * 16 +
                   (lane >> 4) * 4;
      *(f16x4*)&gih[off] = o;
    }
  }
}

// ---------------- char hh chain: 16 blocks (1/team), 512 thr, in-lane gates ----
// Wave w owns units u0=w*16..+16 across ALL 4 gates (rows g*128+u0+l15 of Whh).
// C-layout (verified): acc[g][r] -> unit u0+l15, batch (lane>>4)*4+r => the 4
// gates of each (batch,unit) land in ONE lane: cell update fully in-register,
// one barrier per step, zero cross-block sync.
__global__ __launch_bounds__(512)
void k_chain_char(const f16* __restrict__ Whh, const f16* __restrict__ gih,
                  f16* __restrict__ chars, float* __restrict__ c_save,
                  int dir, int sbase) {
  const int teamc = blockIdx.x;
  const int tid = threadIdx.x, lane = tid & 63, wave = tid >> 6;
  const int l15 = lane & 15, kb = (lane >> 4) * 8;
  const int u0 = wave * 16;
  const int bq = lane >> 4;  // batch quad
  const int cbase = dir ? 128 : 0;

  __shared__ f16 hs[2][16][136];

  f16x8 fh[4][4];
#pragma unroll
  for (int g = 0; g < 4; ++g)
#pragma unroll
    for (int ks = 0; ks < 4; ++ks)
      fh[g][ks] = *(const f16x8*)&Whh[(g * 128 + u0 + l15) * 128 + ks * 32 + kb];

  float c[4];
  if (sbase) {
#pragma unroll
    for (int r = 0; r < 4; ++r)
      c[r] = c_save[(teamc * 128 + u0 + l15) * 16 + bq * 4 + r];
    const int t_prev = dir ? (256 - sbase) : (sbase - 1);
    int b = tid >> 5, u4 = (tid & 31) * 4;
    *(f16x4*)&hs[0][b][u4] =
        *(const f16x4*)&chars[((size_t)(teamc * 256 + t_prev) * 16 + b) * 256 + cbase + u4];
  } else {
#pragma unroll
    for (int r = 0; r < 4; ++r) c[r] = 0.f;
    int b = tid >> 5, u4 = (tid & 31) * 4;
    f16x4 z = {};
    *(f16x4*)&hs[0][b][u4] = z;
  }
  __syncthreads();

  f16x4 gcur[4], gnext[4];
#pragma unroll
  for (int g = 0; g < 4; ++g)
    gcur[g] = *(const f16x4*)&gih[((size_t)(teamc * 128 + 0) * 512 + g * 128 + u0 + l15) * 16 +
                                  bq * 4];
  int par = 0;
  for (int st = 0; st < 128; ++st) {
    const int s = sbase + st;
    if (st < 127) {
#pragma unroll
      for (int g = 0; g < 4; ++g)
        gnext[g] = *(const f16x4*)&gih[((size_t)(teamc * 128 + st + 1) * 512 + g * 128 + u0 +
                                        l15) * 16 + bq * 4];
    }
    f16x8 ah[4];
#pragma unroll
    for (int ks = 0; ks < 4; ++ks) ah[ks] = *(const f16x8*)&hs[par][l15][ks * 32 + kb];
    f32x4 acc[4];
#pragma unroll
    for (int g = 0; g < 4; ++g) {
      f32x4 a = {(float)gcur[g][0], (float)gcur[g][1], (float)gcur[g][2], (float)gcur[g][3]};
      acc[g] = a;
    }
#pragma unroll
    for (int ks = 0; ks < 4; ++ks)
#pragma unroll
      for (int g = 0; g < 4; ++g)
        acc[g] = __builtin_amdgcn_mfma_f32_16x16x32_f16(ah[ks], fh[g][ks], acc[g], 0, 0, 0);
    // in-lane cell: gates i,f,g,o of (batch bq*4+r, unit u0+l15) all local
    const int t_out = dir ? (255 - s) : s;
#pragma unroll
    for (int r = 0; r < 4; ++r) {
      float cc = sigf(acc[1][r]) * c[r] + sigf(acc[0][r]) * tanhf2(acc[2][r]);
      c[r] = cc;
      f16 hv = (f16)(sigf(acc[3][r]) * tanhf2(cc));
      int b = bq * 4 + r;
      chars[((size_t)(teamc * 256 + t_out) * 16 + b) * 256 + cbase + u0 + l15] = hv;
      hs[par ^ 1][b][u0 + l15] = hv;
    }
#pragma unroll
    for (int g = 0; g < 4; ++g) gcur[g] = gnext[g];
    par ^= 1;
    __syncthreads();
  }
#pragma unroll
  for (int r = 0; r < 4; ++r)
    c_save[(teamc * 128 + u0 + l15) * 16 + bq * 4 + r] = c[r];
}

// ---------------- sub + word LSTM (UNCHANGED from R8: proven 846us) ----------
__global__ __launch_bounds__(256, 1)
void k_subword(const f16* __restrict__ wbuf, const f16* __restrict__ chars,
               const int* __restrict__ golds,
               const float* __restrict__ b_sub, const float* __restrict__ b_wrd,
               unsigned* __restrict__ pub, unsigned* __restrict__ flags,
               f16* __restrict__ H2) {
  const int team = blockIdx.x >> 4;
  const int q = blockIdx.x & 15;
  const int m0 = team * 16;
  const int h0 = q * 16;
  const int tid = threadIdx.x, lane = tid & 63, wave = tid >> 6;
  const int l15 = lane & 15, kb = (lane >> 4) * 8;

  const f16* sWih = wbuf + 262144;
  const f16* sWhh = wbuf + 524288;
  const f16* wWih = wbuf + 786432;
  const f16* wWhh = wbuf + 1048576;

  __shared__ f16 xs_s[16][264];
  __shared__ f16 h1_s[16][264];
  __shared__ f16 wh_s[16][264];
  __shared__ float gexS[16][68];
  __shared__ float gexW[16][68];
  __shared__ int golds_s[16][256];

  f32x4 fsi[8], fsh[8], fwi[8], fwh[8];
  const int wr = wave * 256 + h0 + l15;
#pragma unroll
  for (int ks = 0; ks < 8; ++ks) {
    fsi[ks] = *(const volatile f32x4*)&sWih[wr * 256 + ks * 32 + kb];
    fsh[ks] = *(const volatile f32x4*)&sWhh[wr * 256 + ks * 32 + kb];
    fwi[ks] = *(const volatile f32x4*)&wWih[wr * 256 + ks * 32 + kb];
    fwh[ks] = *(const volatile f32x4*)&wWhh[wr * 256 + ks * 32 + kb];
  }
  const float bS = b_sub[wr], bW = b_wrd[wr];

  for (int i = tid; i < 16 * 256; i += 256)
    golds_s[i >> 8][i & 255] = golds[(m0 + (i >> 8)) * S_LEN + (i & 255)];
  for (int i = tid; i < 16 * 264; i += 256) {
    ((f16*)xs_s)[i] = (f16)0.f;
    ((f16*)h1_s)[i] = (f16)0.f;
    ((f16*)wh_s)[i] = (f16)0.f;
  }
  const int cm = tid >> 4, cj = tid & 15;
  const int sr = tid >> 4;
  const int sc = (tid & 15) * 16;
  float c_sub = 0.f, c_wrd = 0.f, wh_reg = 0.f;
  __syncthreads();

  for (int i = 0; i <= S_LEN; ++i) {
    const bool doW = (i > 0), doS = (i < S_LEN);
    const int slotbase = ((i & 1) * 16 + team) << 12;

    f16x4 chpre[4];
    if (doS) {
#pragma unroll
      for (int p = 0; p < 4; ++p)
        chpre[p] = *(const f16x4*)&chars[(size_t)(((team * S_LEN + i) * 16 + sr) * 256) +
                                         sc + p * 4];
    }

    f32x4 accW = {bW, bW, bW, bW};
    f32x4 accS = {bS, bS, bS, bS};
    if (doW) {
#pragma unroll
      for (int ks = 0; ks < 8; ++ks) {
        f16x8 a1 = *(const f16x8*)&h1_s[l15][ks * 32 + kb];
        f16x8 aw = *(const f16x8*)&wh_s[l15][ks * 32 + kb];
        accW = __builtin_amdgcn_mfma_f32_16x16x32_f16(
            a1, __builtin_bit_cast(f16x8, fwi[ks]), accW, 0, 0, 0);
        accW = __builtin_amdgcn_mfma_f32_16x16x32_f16(
            aw, __builtin_bit_cast(f16x8, fwh[ks]), accW, 0, 0, 0);
      }
    }
    if (doS) {
      const bool keep = (i > 0) && (golds_s[l15][i > 0 ? i - 1 : 0] == 0);
      f16x8 z8 = {};
#pragma unroll
      for (int ks = 0; ks < 8; ++ks) {
        f16x8 axv = *(const f16x8*)&xs_s[l15][ks * 32 + kb];
        f16x8 a1 = *(const f16x8*)&h1_s[l15][ks * 32 + kb];
        a1 = keep ? a1 : z8;
        accS = __builtin_amdgcn_mfma_f32_16x16x32_f16(
            axv, __builtin_bit_cast(f16x8, fsi[ks]), accS, 0, 0, 0);
        accS = __builtin_amdgcn_mfma_f32_16x16x32_f16(
            a1, __builtin_bit_cast(f16x8, fsh[ks]), accS, 0, 0, 0);
      }
    }
#pragma unroll
    for (int r = 0; r < 4; ++r) {
      if (doW) gexW[(lane >> 4) * 4 + r][wave * 16 + l15] = accW[r];
      if (doS) gexS[(lane >> 4) * 4 + r][wave * 16 + l15] = accS[r];
    }
    __syncthreads();  // B1

    const int gprev = (i > 0) ? golds_s[cm][i - 1] : 1;
    if (doW) {
      float gi = gexW[cm][cj], gf = gexW[cm][16 + cj], gg = gexW[cm][32 + cj],
            go = gexW[cm][48 + cj];
      float c2 = sigf(gf) * c_wrd + sigf(gi) * tanhf2(gg);
      float h2 = sigf(go) * tanhf2(c2);
      bool adv = (gprev != 0);
      if (adv) { c_wrd = c2; wh_reg = h2; }
      H2[(size_t)(i - 1) * BATCH * 256 + (m0 + cm) * 256 + h0 + cj] = (f16)h2;
    }
    if (doS) {
      float gi = gexS[cm][cj], gf = gexS[cm][16 + cj], gg = gexS[cm][32 + cj],
            go = gexS[cm][48 + cj];
      float cp = (gprev == 0) ? c_sub : 0.f;
      float c1 = sigf(gf) * cp + sigf(gi) * tanhf2(gg);
      c_sub = c1;
      f16 h1 = (f16)(sigf(go) * tanhf2(c1));
      unsigned val = ((unsigned)__builtin_bit_cast(unsigned short, h1) << 16) |
                     (unsigned)__builtin_bit_cast(unsigned short, (f16)wh_reg);
      __hip_atomic_store(&pub[slotbase + cm * 256 + h0 + cj], val, __ATOMIC_RELAXED,
                         __HIP_MEMORY_SCOPE_AGENT);
    }
    __syncthreads();  // B2

    if (doS) {
      if (tid == 0)
        __hip_atomic_store(&flags[(team * 16 + q) * 16], (unsigned)(i + 1), __ATOMIC_RELAXED,
                           __HIP_MEMORY_SCOPE_AGENT);
      if (tid < 64) {
        const unsigned tgt = (unsigned)(i + 1);
        while (true) {
          unsigned v = tgt;
          if (lane < 16)
            v = __hip_atomic_load(&flags[(team * 16 + lane) * 16], __ATOMIC_RELAXED,
                                  __HIP_MEMORY_SCOPE_AGENT);
          if (__all(v >= tgt)) break;
          __builtin_amdgcn_s_sleep(1);
        }
      }
      asm volatile("" ::: "memory");
      __syncthreads();  // B3
      union { unsigned u[8]; f16 h[16]; } wv;
#pragma unroll
      for (int k = 0; k < 8; ++k)
        wv.u[k] = __hip_atomic_load(&pub[slotbase + sr * 256 + sc + k], __ATOMIC_RELAXED,
                                    __HIP_MEMORY_SCOPE_AGENT);
      union { unsigned short s[8]; f16x8 v; } uh, uw;
#pragma unroll
      for (int k = 0; k < 8; ++k) {
        unsigned u = wv.u[k];
        uh.s[k] = (unsigned short)(u >> 16);
        uw.s[k] = (unsigned short)(u & 0xffffu);
      }
      *(f16x8*)&h1_s[sr][sc] = uh.v;
      *(f16x8*)&wh_s[sr][sc] = uw.v;
#pragma unroll
      for (int k = 0; k < 8; ++k)
        wv.u[k] = __hip_atomic_load(&pub[slotbase + sr * 256 + sc + 8 + k], __ATOMIC_RELAXED,
                                    __HIP_MEMORY_SCOPE_AGENT);
#pragma unroll
      for (int k = 0; k < 8; ++k) {
        unsigned u = wv.u[k];
        uh.s[k] = (unsigned short)(u >> 16);
        uw.s[k] = (unsigned short)(u & 0xffffu);
      }
      *(f16x8*)&h1_s[sr][sc + 8] = uh.v;
      *(f16x8*)&wh_s[sr][sc + 8] = uw.v;
#pragma unroll
      for (int p = 0; p < 4; ++p) *(f16x4*)&xs_s[sr][sc + p * 4] = chpre[p];
      __syncthreads();  // B4
    }
  }
}

// ---------------- classifier (unchanged) ----------------
__global__ __launch_bounds__(256)
void k_cls(const f16* __restrict__ H2, const f16* __restrict__ chars,
           const float* __restrict__ clsW, const float* __restrict__ clsb,
           float* __restrict__ out) {
  const int w = (blockIdx.x << 2) | (threadIdx.x >> 6);  // row = t*B + b
  const int lane = threadIdx.x & 63;
  const int t = w >> 8, b = w & 255;
  const f16* h2p = H2 + (size_t)w * 256;
  const f16* chp = chars + (size_t)(((b >> 4) * S_LEN + t) * 16 + (b & 15)) * 256;
  float s0 = 0.f, s1 = 0.f;
  f16x4 hv = *(const f16x4*)&h2p[lane * 4];
  f16x4 cv = *(const f16x4*)&chp[lane * 4];
#pragma unroll
  for (int qq = 0; qq < 4; ++qq) {
    int u = lane * 4 + qq;
    s0 += (float)hv[qq] * clsW[u] + (float)cv[qq] * clsW[256 + u];
    s1 += (float)hv[qq] * clsW[512 + u] + (float)cv[qq] * clsW[768 + u];
  }
#pragma unroll
  for (int off = 32; off >= 1; off >>= 1) {
    s0 += __shfl_down(s0, off);
    s1 += __shfl_down(s1, off);
  }
  if (lane == 0) {
    out[((size_t)b * S_LEN + t) * 2 + 0] = s0 + clsb[0];
    out[((size_t)b * S_LEN + t) * 2 + 1] = s1 + clsb[1];
  }
}

extern "C" void kernel_launch(void* const* d_in, const int* in_sizes, int n_in,
                              void* d_out, int out_size, void* d_ws, size_t ws_size,
                              hipStream_t stream) {
  const int* insts = (const int*)d_in[0];
  const int* golds = (const int*)d_in[1];
  const float* emb = (const float*)d_in[2];
  const float* wihf = (const float*)d_in[3];
  const float* whhf = (const float*)d_in[4];
  const float* bf = (const float*)d_in[5];
  const float* wihb = (const float*)d_in[6];
  const float* whhb = (const float*)d_in[7];
  const float* bb = (const float*)d_in[8];
  const float* swih = (const float*)d_in[9];
  const float* swhh = (const float*)d_in[10];
  const float* sb = (const float*)d_in[11];
  const float* wwih = (const float*)d_in[12];
  const float* wwhh = (const float*)d_in[13];
  const float* wb = (const float*)d_in[14];
  const float* clsW = (const float*)d_in[15];
  const float* clsb = (const float*)d_in[16];
  float* out = (float*)d_out;

  // workspace layout (bytes)
  const size_t OFF_W = 0;                     // 2,621,440 (weights f16)
  const size_t OFF_XF = 2621440;              // +16,777,216 (Xf; dead after gih kernels)
  const size_t OFF_PUB = OFF_XF + 4194304;    // pub (subword phase, overlaid on Xf)
  const size_t OFF_FLAGS = OFF_PUB + 524288;  // flags
  const size_t OFF_CHARS = 19398656;          // +33,554,432 chars [teamc][t][16][256]
  const size_t OFF_A = 52953088;              // +33,554,432: Gih buffer, then H2
  const size_t OFF_TAIL = 86507520;           // c_save 131,072
  const size_t TOTAL = 87048192;
  if (ws_size < TOTAL) return;

  char* ws = (char*)d_ws;
  f16* wbuf = (f16*)(ws + OFF_W);
  f16* Xf = (f16*)(ws + OFF_XF);
  f16* chars = (f16*)(ws + OFF_CHARS);
  f16* gih = (f16*)(ws + OFF_A);
  f16* H2 = (f16*)(ws + OFF_A);
  float* c_save = (float*)(ws + OFF_TAIL);
  unsigned* pub = (unsigned*)(ws + OFF_PUB);
  unsigned* flags = (unsigned*)(ws + OFF_FLAGS);

  hipLaunchKernelGGL(k_convert, dim3(1024), dim3(256), 0, stream, wihf, whhf, wihb, whhb,
                     swih, swhh, wwih, wwhh, wbuf);
  hipLaunchKernelGGL(k_gather, dim3(8192), dim3(256), 0, stream, insts, emb, Xf);

  // char phase: per direction, per 128-step half: ih-precompute GEMM + hh chain
  const f16* wihF = wbuf + 0;      const f16* whhF = wbuf + 65536;
  const f16* wihB = wbuf + 131072; const f16* whhB = wbuf + 196608;
  hipLaunchKernelGGL(k_gih_char, dim3(256), dim3(256), 0, stream, wihF, bf, Xf, gih, 0, 0);
  hipLaunchKernelGGL(k_chain_char, dim3(16), dim3(512), 0, stream, whhF, gih, chars, c_save, 0, 0);
  hipLaunchKernelGGL(k_gih_char, dim3(256), dim3(256), 0, stream, wihF, bf, Xf, gih, 0, 128);
  hipLaunchKernelGGL(k_chain_char, dim3(16), dim3(512), 0, stream, whhF, gih, chars, c_save, 0, 128);
  hipLaunchKernelGGL(k_gih_char, dim3(256), dim3(256), 0, stream, wihB, bb, Xf, gih, 1, 0);
  hipLaunchKernelGGL(k_chain_char, dim3(16), dim3(512), 0, stream, whhB, gih, chars, c_save, 1, 0);
  hipLaunchKernelGGL(k_gih_char, dim3(256), dim3(256), 0, stream, wihB, bb, Xf, gih, 1, 128);
  hipLaunchKernelGGL(k_chain_char, dim3(16), dim3(512), 0, stream, whhB, gih, chars, c_save, 1, 128);

  // sub+word phase (unchanged R8 structure); flags live in dead Xf region
  hipLaunchKernelGGL(k_zero, dim3(16), dim3(256), 0, stream, (unsigned*)(ws + OFF_FLAGS),
                     4096);
  hipLaunchKernelGGL(k_subword, dim3(256), dim3(256), 0, stream, wbuf, chars, golds, sb, wb,
                     pub, flags, H2);
  hipLaunchKernelGGL(k_cls, dim3(16384), dim3(256), 0, stream, H2, chars, clsW, clsb, out);
}

// Round 10
// 1369.855 us; speedup vs baseline: 1.5758x; 1.5758x over previous
//
#include <hip/hip_runtime.h>

#define S_LEN 256
#define BATCH 256

typedef _Float16 f16;
typedef _Float16 f16x8 __attribute__((ext_vector_type(8)));
typedef _Float16 f16x4 __attribute__((ext_vector_type(4)));
typedef float f32x4 __attribute__((ext_vector_type(4)));
typedef unsigned u32x4 __attribute__((ext_vector_type(4)));

__device__ inline float sigf(float x) { return 1.f / (1.f + __expf(-x)); }
__device__ inline float tanhf2(float x) { return 2.f * sigf(2.f * x) - 1.f; }

// LDS-only barrier: drain ds ops, leave global loads/stores in flight.
#define BARRIER_LGKM() asm volatile("s_waitcnt lgkmcnt(0)\n\ts_barrier" ::: "memory")

// ---------------- weight f32 -> f16 conversion ----------------
// dst layout (f16 elems): wihf@0, whhf@65536, wihb@131072, whhb@196608,
// swih@262144, swhh@524288, wwih@786432, wwhh@1048576  (total 1310720)
__global__ void k_convert(const float* __restrict__ w3, const float* __restrict__ w4,
                          const float* __restrict__ w6, const float* __restrict__ w7,
                          const float* __restrict__ w9, const float* __restrict__ w10,
                          const float* __restrict__ w12, const float* __restrict__ w13,
                          f16* __restrict__ dst) {
  int i = blockIdx.x * blockDim.x + threadIdx.x;
  const int n = 1310720;
  for (; i < n; i += gridDim.x * blockDim.x) {
    float v;
    if (i < 262144) {
      int m = i >> 16, j = i & 65535;
      v = (m == 0 ? w3 : m == 1 ? w4 : m == 2 ? w6 : w7)[j];
    } else {
      int k = i - 262144;
      int m = k >> 18, j = k & 262143;
      v = (m == 0 ? w9 : m == 1 ? w10 : m == 2 ? w12 : w13)[j];
    }
    dst[i] = (f16)v;
  }
}

__global__ void k_zero(unsigned* __restrict__ p, int n) {
  int i = blockIdx.x * blockDim.x + threadIdx.x;
  for (; i < n; i += gridDim.x * blockDim.x) p[i] = 0u;
}

// ---------------- embedding gather -> Xf [t][b][128] f16 ----------------
__global__ void k_gather(const int* __restrict__ insts, const float* __restrict__ emb,
                         f16* __restrict__ Xf) {
  int gid = blockIdx.x * blockDim.x + threadIdx.x;  // 0..2097151
  int row = gid >> 5;                               // t*B + b
  int ch = gid & 31;
  int t = row >> 8, b = row & 255;
  int v = insts[b * S_LEN + t];
  const float* src = emb + (size_t)v * 128 + ch * 4;
  f16x4 d;
  d[0] = (f16)src[0]; d[1] = (f16)src[1]; d[2] = (f16)src[2]; d[3] = (f16)src[3];
  *(f16x4*)&Xf[(size_t)row * 128 + ch * 4] = d;
}

// ---------------- char ih precompute: gih[dir][team][srel<64][512][16] ----------------
// Both directions in one launch (256 blocks), 64 chain-steps per launch.
__global__ __launch_bounds__(256)
void k_gih_char(const f16* __restrict__ wbuf, const float* __restrict__ bias_f,
                const float* __restrict__ bias_b, const f16* __restrict__ Xf,
                f16* __restrict__ gih, int sbase) {
  const int team = blockIdx.x & 15;
  const int tc = (blockIdx.x >> 4) & 3;   // 4 chunks of 16 steps
  const int gc = (blockIdx.x >> 6) & 1;   // gate-row half
  const int dr = blockIdx.x >> 7;         // direction
  const int m0 = team * 16;
  const f16* Wih = wbuf + (dr ? 131072 : 0);
  const float* bias = dr ? bias_b : bias_f;
  const int lane = threadIdx.x & 63, wave = threadIdx.x >> 6;
  const int l15 = lane & 15, kb = (lane >> 4) * 8;
  const int rbase = gc * 256 + wave * 64;

  f16x8 fw[4][4];
  float bv[4];
#pragma unroll
  for (int tt = 0; tt < 4; ++tt) {
    int col = rbase + tt * 16 + l15;
    bv[tt] = bias[col];
#pragma unroll
    for (int ks = 0; ks < 4; ++ks)
      fw[tt][ks] = *(const f16x8*)&Wih[col * 128 + ks * 32 + kb];
  }

  for (int st = 0; st < 16; ++st) {
    const int srel = tc * 16 + st;
    const int s = sbase + srel;
    const int t_in = dr ? (255 - s) : s;
    f32x4 acc[4];
#pragma unroll
    for (int tt = 0; tt < 4; ++tt) { f32x4 a = {bv[tt], bv[tt], bv[tt], bv[tt]}; acc[tt] = a; }
    f16x8 ax[4];
#pragma unroll
    for (int ks = 0; ks < 4; ++ks)
      ax[ks] = *(const f16x8*)&Xf[(size_t)t_in * BATCH * 128 + (m0 + l15) * 128 + ks * 32 + kb];
#pragma unroll
    for (int ks = 0; ks < 4; ++ks)
#pragma unroll
      for (int tt = 0; tt < 4; ++tt)
        acc[tt] = __builtin_amdgcn_mfma_f32_16x16x32_f16(ax[ks], fw[tt][ks], acc[tt], 0, 0, 0);
#pragma unroll
    for (int tt = 0; tt < 4; ++tt) {
      f16x4 o;
#pragma unroll
      for (int r = 0; r < 4; ++r) o[r] = (f16)acc[tt][r];
      size_t off = ((((size_t)dr * 16 + team) * 64 + srel) * 512 + rbase + tt * 16 + l15) * 16 +
                   (lane >> 4) * 4;
      *(f16x4*)&gih[off] = o;
    }
  }
}

// ---------------- char hh chain: 32 blocks (dir x team), 512 thr ----------------
// In-lane gates (wave owns 16 units x 4 gates); one LDS-only barrier per step:
// chars stores + gih prefetch stay in flight (no vmcnt drain per step).
__global__ __launch_bounds__(512)
void k_chain_char(const f16* __restrict__ wbuf, const f16* __restrict__ gih,
                  f16* __restrict__ chars, float* __restrict__ c_save, int sbase) {
  const int dr = blockIdx.x >> 4;
  const int teamc = blockIdx.x & 15;
  const f16* Whh = wbuf + (dr ? 196608 : 65536);
  const int tid = threadIdx.x, lane = tid & 63, wave = tid >> 6;
  const int l15 = lane & 15, kb = (lane >> 4) * 8;
  const int u0 = wave * 16;
  const int bq = lane >> 4;  // batch quad
  const int cbase = dr ? 128 : 0;

  __shared__ f16 hs[2][16][136];

  f16x8 fh[4][4];
#pragma unroll
  for (int g = 0; g < 4; ++g)
#pragma unroll
    for (int ks = 0; ks < 4; ++ks)
      fh[g][ks] = *(const f16x8*)&Whh[(g * 128 + u0 + l15) * 128 + ks * 32 + kb];

  float c[4];
  const size_t csoff = (((size_t)dr * 16 + teamc) * 128 + u0 + l15) * 16 + bq * 4;
  if (sbase) {
#pragma unroll
    for (int r = 0; r < 4; ++r) c[r] = c_save[csoff + r];
    const int t_prev = dr ? (256 - sbase) : (sbase - 1);
    int b = tid >> 5, u4 = (tid & 31) * 4;
    *(f16x4*)&hs[0][b][u4] =
        *(const f16x4*)&chars[((size_t)(teamc * 256 + t_prev) * 16 + b) * 256 + cbase + u4];
  } else {
#pragma unroll
    for (int r = 0; r < 4; ++r) c[r] = 0.f;
    int b = tid >> 5, u4 = (tid & 31) * 4;
    f16x4 z = {};
    *(f16x4*)&hs[0][b][u4] = z;
  }
  __syncthreads();

  const f16* gbase = gih + (((size_t)dr * 16 + teamc) * 64) * 512 * 16;
  f16x4 gcur[4], gnext[4];
#pragma unroll
  for (int g = 0; g < 4; ++g)
    gcur[g] = *(const f16x4*)&gbase[((size_t)0 * 512 + g * 128 + u0 + l15) * 16 + bq * 4];
  int par = 0;
  for (int st = 0; st < 64; ++st) {
    const int s = sbase + st;
    if (st < 63) {
#pragma unroll
      for (int g = 0; g < 4; ++g)
        gnext[g] =
            *(const f16x4*)&gbase[((size_t)(st + 1) * 512 + g * 128 + u0 + l15) * 16 + bq * 4];
    }
    f16x8 ah[4];
#pragma unroll
    for (int ks = 0; ks < 4; ++ks) ah[ks] = *(const f16x8*)&hs[par][l15][ks * 32 + kb];
    f32x4 acc[4];
#pragma unroll
    for (int g = 0; g < 4; ++g) {
      f32x4 a = {(float)gcur[g][0], (float)gcur[g][1], (float)gcur[g][2], (float)gcur[g][3]};
      acc[g] = a;
    }
#pragma unroll
    for (int ks = 0; ks < 4; ++ks)
#pragma unroll
      for (int g = 0; g < 4; ++g)
        acc[g] = __builtin_amdgcn_mfma_f32_16x16x32_f16(ah[ks], fh[g][ks], acc[g], 0, 0, 0);
    // in-lane cell: gates i,f,g,o of (batch bq*4+r, unit u0+l15) all local
    const int t_out = dr ? (255 - s) : s;
#pragma unroll
    for (int r = 0; r < 4; ++r) {
      float cc = sigf(acc[1][r]) * c[r] + sigf(acc[0][r]) * tanhf2(acc[2][r]);
      c[r] = cc;
      f16 hv = (f16)(sigf(acc[3][r]) * tanhf2(cc));
      int b = bq * 4 + r;
      chars[((size_t)(teamc * 256 + t_out) * 16 + b) * 256 + cbase + u0 + l15] = hv;
      hs[par ^ 1][b][u0 + l15] = hv;
    }
#pragma unroll
    for (int g = 0; g < 4; ++g) gcur[g] = gnext[g];
    par ^= 1;
    BARRIER_LGKM();  // LDS-only: hh recurrence ordered, global traffic in flight
  }
#pragma unroll
  for (int r = 0; r < 4; ++r) c_save[csoff + r] = c[r];
}

// ---------------- sub + word LSTM (R8 version verbatim: proven 846us) ----------
__global__ __launch_bounds__(256, 1)
void k_subword(const f16* __restrict__ wbuf, const f16* __restrict__ chars,
               const int* __restrict__ golds,
               const float* __restrict__ b_sub, const float* __restrict__ b_wrd,
               unsigned* __restrict__ pub, unsigned* __restrict__ flags,
               f16* __restrict__ H2) {
  const int team = blockIdx.x >> 4;
  const int q = blockIdx.x & 15;
  const int m0 = team * 16;
  const int h0 = q * 16;
  const int tid = threadIdx.x, lane = tid & 63, wave = tid >> 6;
  const int l15 = lane & 15, kb = (lane >> 4) * 8;

  const f16* sWih = wbuf + 262144;
  const f16* sWhh = wbuf + 524288;
  const f16* wWih = wbuf + 786432;
  const f16* wWhh = wbuf + 1048576;

  __shared__ f16 xs_s[16][264];
  __shared__ f16 h1_s[16][264];
  __shared__ f16 wh_s[16][264];
  __shared__ float gexS[16][68];
  __shared__ float gexW[16][68];
  __shared__ int golds_s[16][256];

  f32x4 fsi[8], fsh[8], fwi[8], fwh[8];
  const int wr = wave * 256 + h0 + l15;
#pragma unroll
  for (int ks = 0; ks < 8; ++ks) {
    fsi[ks] = *(const volatile f32x4*)&sWih[wr * 256 + ks * 32 + kb];
    fsh[ks] = *(const volatile f32x4*)&sWhh[wr * 256 + ks * 32 + kb];
    fwi[ks] = *(const volatile f32x4*)&wWih[wr * 256 + ks * 32 + kb];
    fwh[ks] = *(const volatile f32x4*)&wWhh[wr * 256 + ks * 32 + kb];
  }
  const float bS = b_sub[wr], bW = b_wrd[wr];

  for (int i = tid; i < 16 * 256; i += 256)
    golds_s[i >> 8][i & 255] = golds[(m0 + (i >> 8)) * S_LEN + (i & 255)];
  for (int i = tid; i < 16 * 264; i += 256) {
    ((f16*)xs_s)[i] = (f16)0.f;
    ((f16*)h1_s)[i] = (f16)0.f;
    ((f16*)wh_s)[i] = (f16)0.f;
  }
  const int cm = tid >> 4, cj = tid & 15;
  const int sr = tid >> 4;
  const int sc = (tid & 15) * 16;
  float c_sub = 0.f, c_wrd = 0.f, wh_reg = 0.f;
  __syncthreads();

  for (int i = 0; i <= S_LEN; ++i) {
    const bool doW = (i > 0), doS = (i < S_LEN);
    const int slotbase = ((i & 1) * 16 + team) << 12;

    f16x4 chpre[4];
    if (doS) {
#pragma unroll
      for (int p = 0; p < 4; ++p)
        chpre[p] = *(const f16x4*)&chars[(size_t)(((team * S_LEN + i) * 16 + sr) * 256) +
                                         sc + p * 4];
    }

    f32x4 accW = {bW, bW, bW, bW};
    f32x4 accS = {bS, bS, bS, bS};
    if (doW) {
#pragma unroll
      for (int ks = 0; ks < 8; ++ks) {
        f16x8 a1 = *(const f16x8*)&h1_s[l15][ks * 32 + kb];
        f16x8 aw = *(const f16x8*)&wh_s[l15][ks * 32 + kb];
        accW = __builtin_amdgcn_mfma_f32_16x16x32_f16(
            a1, __builtin_bit_cast(f16x8, fwi[ks]), accW, 0, 0, 0);
        accW = __builtin_amdgcn_mfma_f32_16x16x32_f16(
            aw, __builtin_bit_cast(f16x8, fwh[ks]), accW, 0, 0, 0);
      }
    }
    if (doS) {
      const bool keep = (i > 0) && (golds_s[l15][i > 0 ? i - 1 : 0] == 0);
      f16x8 z8 = {};
#pragma unroll
      for (int ks = 0; ks < 8; ++ks) {
        f16x8 axv = *(const f16x8*)&xs_s[l15][ks * 32 + kb];
        f16x8 a1 = *(const f16x8*)&h1_s[l15][ks * 32 + kb];
        a1 = keep ? a1 : z8;
        accS = __builtin_amdgcn_mfma_f32_16x16x32_f16(
            axv, __builtin_bit_cast(f16x8, fsi[ks]), accS, 0, 0, 0);
        accS = __builtin_amdgcn_mfma_f32_16x16x32_f16(
            a1, __builtin_bit_cast(f16x8, fsh[ks]), accS, 0, 0, 0);
      }
    }
#pragma unroll
    for (int r = 0; r < 4; ++r) {
      if (doW) gexW[(lane >> 4) * 4 + r][wave * 16 + l15] = accW[r];
      if (doS) gexS[(lane >> 4) * 4 + r][wave * 16 + l15] = accS[r];
    }
    __syncthreads();  // B1

    const int gprev = (i > 0) ? golds_s[cm][i - 1] : 1;
    if (doW) {
      float gi = gexW[cm][cj], gf = gexW[cm][16 + cj], gg = gexW[cm][32 + cj],
            go = gexW[cm][48 + cj];
      float c2 = sigf(gf) * c_wrd + sigf(gi) * tanhf2(gg);
      float h2 = sigf(go) * tanhf2(c2);
      bool adv = (gprev != 0);
      if (adv) { c_wrd = c2; wh_reg = h2; }
      H2[(size_t)(i - 1) * BATCH * 256 + (m0 + cm) * 256 + h0 + cj] = (f16)h2;
    }
    if (doS) {
      float gi = gexS[cm][cj], gf = gexS[cm][16 + cj], gg = gexS[cm][32 + cj],
            go = gexS[cm][48 + cj];
      float cp = (gprev == 0) ? c_sub : 0.f;
      float c1 = sigf(gf) * cp + sigf(gi) * tanhf2(gg);
      c_sub = c1;
      f16 h1 = (f16)(sigf(go) * tanhf2(c1));
      unsigned val = ((unsigned)__builtin_bit_cast(unsigned short, h1) << 16) |
                     (unsigned)__builtin_bit_cast(unsigned short, (f16)wh_reg);
      __hip_atomic_store(&pub[slotbase + cm * 256 + h0 + cj], val, __ATOMIC_RELAXED,
                         __HIP_MEMORY_SCOPE_AGENT);
    }
    __syncthreads();  // B2: publish stores drained (vmcnt 0 at barrier)

    if (doS) {
      if (tid == 0)
        __hip_atomic_store(&flags[(team * 16 + q) * 16], (unsigned)(i + 1), __ATOMIC_RELAXED,
                           __HIP_MEMORY_SCOPE_AGENT);
      if (tid < 64) {
        const unsigned tgt = (unsigned)(i + 1);
        while (true) {
          unsigned v = tgt;
          if (lane < 16)
            v = __hip_atomic_load(&flags[(team * 16 + lane) * 16], __ATOMIC_RELAXED,
                                  __HIP_MEMORY_SCOPE_AGENT);
          if (__all(v >= tgt)) break;
          __builtin_amdgcn_s_sleep(1);
        }
      }
      asm volatile("" ::: "memory");
      __syncthreads();  // B3
      // staging: 64B per thread via 4 wide coherent loads (sc0 sc1), single drain
      u32x4 w0, w1, w2, w3;
      {
        const unsigned* pb = &pub[slotbase + sr * 256 + sc];
        asm volatile(
            "global_load_dwordx4 %0, %4, off sc0 sc1\n\t"
            "global_load_dwordx4 %1, %5, off sc0 sc1\n\t"
            "global_load_dwordx4 %2, %6, off sc0 sc1\n\t"
            "global_load_dwordx4 %3, %7, off sc0 sc1\n\t"
            "s_waitcnt vmcnt(0)"
            : "=&v"(w0), "=&v"(w1), "=&v"(w2), "=&v"(w3)
            : "v"(pb), "v"(pb + 4), "v"(pb + 8), "v"(pb + 12));
      }
      union { unsigned short s[8]; f16x8 v; } uh0, uw0, uh1, uw1;
#pragma unroll
      for (int k = 0; k < 4; ++k) {
        uh0.s[k] = (unsigned short)(w0[k] >> 16);
        uw0.s[k] = (unsigned short)(w0[k] & 0xffffu);
        uh0.s[4 + k] = (unsigned short)(w1[k] >> 16);
        uw0.s[4 + k] = (unsigned short)(w1[k] & 0xffffu);
        uh1.s[k] = (unsigned short)(w2[k] >> 16);
        uw1.s[k] = (unsigned short)(w2[k] & 0xffffu);
        uh1.s[4 + k] = (unsigned short)(w3[k] >> 16);
        uw1.s[4 + k] = (unsigned short)(w3[k] & 0xffffu);
      }
      *(f16x8*)&h1_s[sr][sc] = uh0.v;
      *(f16x8*)&wh_s[sr][sc] = uw0.v;
      *(f16x8*)&h1_s[sr][sc + 8] = uh1.v;
      *(f16x8*)&wh_s[sr][sc + 8] = uw1.v;
#pragma unroll
      for (int p = 0; p < 4; ++p) *(f16x4*)&xs_s[sr][sc + p * 4] = chpre[p];
      __syncthreads();  // B4
    }
  }
}

// ---------------- classifier (unchanged) ----------------
__global__ __launch_bounds__(256)
void k_cls(const f16* __restrict__ H2, const f16* __restrict__ chars,
           const float* __restrict__ clsW, const float* __restrict__ clsb,
           float* __restrict__ out) {
  const int w = (blockIdx.x << 2) | (threadIdx.x >> 6);  // row = t*B + b
  const int lane = threadIdx.x & 63;
  const int t = w >> 8, b = w & 255;
  const f16* h2p = H2 + (size_t)w * 256;
  const f16* chp = chars + (size_t)(((b >> 4) * S_LEN + t) * 16 + (b & 15)) * 256;
  float s0 = 0.f, s1 = 0.f;
  f16x4 hv = *(const f16x4*)&h2p[lane * 4];
  f16x4 cv = *(const f16x4*)&chp[lane * 4];
#pragma unroll
  for (int qq = 0; qq < 4; ++qq) {
    int u = lane * 4 + qq;
    s0 += (float)hv[qq] * clsW[u] + (float)cv[qq] * clsW[256 + u];
    s1 += (float)hv[qq] * clsW[512 + u] + (float)cv[qq] * clsW[768 + u];
  }
#pragma unroll
  for (int off = 32; off >= 1; off >>= 1) {
    s0 += __shfl_down(s0, off);
    s1 += __shfl_down(s1, off);
  }
  if (lane == 0) {
    out[((size_t)b * S_LEN + t) * 2 + 0] = s0 + clsb[0];
    out[((size_t)b * S_LEN + t) * 2 + 1] = s1 + clsb[1];
  }
}

extern "C" void kernel_launch(void* const* d_in, const int* in_sizes, int n_in,
                              void* d_out, int out_size, void* d_ws, size_t ws_size,
                              hipStream_t stream) {
  const int* insts = (const int*)d_in[0];
  const int* golds = (const int*)d_in[1];
  const float* emb = (const float*)d_in[2];
  const float* wihf = (const float*)d_in[3];
  const float* whhf = (const float*)d_in[4];
  const float* bf = (const float*)d_in[5];
  const float* wihb = (const float*)d_in[6];
  const float* whhb = (const float*)d_in[7];
  const float* bb = (const float*)d_in[8];
  const float* swih = (const float*)d_in[9];
  const float* swhh = (const float*)d_in[10];
  const float* sb = (const float*)d_in[11];
  const float* wwih = (const float*)d_in[12];
  const float* wwhh = (const float*)d_in[13];
  const float* wb = (const float*)d_in[14];
  const float* clsW = (const float*)d_in[15];
  const float* clsb = (const float*)d_in[16];
  float* out = (float*)d_out;

  // workspace layout (bytes)
  const size_t OFF_W = 0;                     // 2,621,440 (weights f16)
  const size_t OFF_XF = 2621440;              // +16,777,216 (Xf; dead after gih #4)
  const size_t OFF_PUB = OFF_XF + 4194304;    // pub (subword phase, overlaid on Xf)
  const size_t OFF_FLAGS = OFF_PUB + 524288;  // flags (overlaid on Xf)
  const size_t OFF_CHARS = 19398656;          // +33,554,432 chars [teamc][t][16][256]
  const size_t OFF_A = 52953088;              // +33,554,432: gih (char phase) then H2
  const size_t OFF_TAIL = 86507520;           // c_save 262,144
  const size_t TOTAL = 87048192;
  if (ws_size < TOTAL) return;

  char* ws = (char*)d_ws;
  f16* wbuf = (f16*)(ws + OFF_W);
  f16* Xf = (f16*)(ws + OFF_XF);
  f16* chars = (f16*)(ws + OFF_CHARS);
  f16* gih = (f16*)(ws + OFF_A);
  f16* H2 = (f16*)(ws + OFF_A);
  float* c_save = (float*)(ws + OFF_TAIL);
  unsigned* pub = (unsigned*)(ws + OFF_PUB);
  unsigned* flags = (unsigned*)(ws + OFF_FLAGS);

  hipLaunchKernelGGL(k_convert, dim3(1024), dim3(256), 0, stream, wihf, whhf, wihb, whhb,
                     swih, swhh, wwih, wwhh, wbuf);
  hipLaunchKernelGGL(k_gather, dim3(8192), dim3(256), 0, stream, insts, emb, Xf);

  // char phase: 4 quarter-chunks of 64 steps, both directions concurrent
  for (int sb4 = 0; sb4 < 256; sb4 += 64) {
    hipLaunchKernelGGL(k_gih_char, dim3(256), dim3(256), 0, stream, wbuf, bf, bb, Xf, gih,
                       sb4);
    hipLaunchKernelGGL(k_chain_char, dim3(32), dim3(512), 0, stream, wbuf, gih, chars,
                       c_save, sb4);
  }

  // sub+word phase (R8 structure); flags live in dead Xf region
  hipLaunchKernelGGL(k_zero, dim3(16), dim3(256), 0, stream, (unsigned*)(ws + OFF_FLAGS),
                     4096);
  hipLaunchKernelGGL(k_subword, dim3(256), dim3(256), 0, stream, wbuf, chars, golds, sb, wb,
                     pub, flags, H2);
  hipLaunchKernelGGL(k_cls, dim3(16384), dim3(256), 0, stream, H2, chars, clsW, clsb, out);
}